// Round 16
// baseline (53.841 us; speedup 1.0000x reference)
//
#include <hip/hip_runtime.h>

typedef __attribute__((ext_vector_type(8))) short bf16x8;
typedef __attribute__((ext_vector_type(4))) float f32x4;

union FragU { uint4 q; bf16x8 h; };

__device__ __forceinline__ unsigned short f2bf(float f) {
  unsigned u = __float_as_uint(f);
  u += 0x7FFFu + ((u >> 16) & 1u);   // RNE
  return (unsigned short)(u >> 16);
}
__device__ __forceinline__ unsigned pack2(float lo, float hi) {
  return (unsigned)f2bf(lo) | ((unsigned)f2bf(hi) << 16);
}

// ---------------------------------------------------------------------------
// kX (r8-verbatim): one-shot cast into MFMA-fragment layouts.
// ---------------------------------------------------------------------------
__global__ __launch_bounds__(256) void kX(
    const float* __restrict__ x, const float* __restrict__ W1,
    const float* __restrict__ W2, uint4* __restrict__ xbf,
    uint4* __restrict__ w1f, uint4* __restrict__ w2f)
{
  const int u = blockIdx.x * 256 + threadIdx.x;
  if (u < 131072) {            // x frags: 16b x 16t x 8c x 64l
    const int l = u & 63, c = (u >> 6) & 7, t = (u >> 9) & 15, b = u >> 13;
    const int fr = l & 15, fq = l >> 4;
    const float* p = x + (size_t)((b * 16 + t) * 16 + fr) * 256 + c * 32 + fq * 8;
    float4 va = *(const float4*)p;
    float4 vb = *(const float4*)(p + 4);
    xbf[u] = make_uint4(pack2(va.x, va.y), pack2(va.z, va.w),
                        pack2(vb.x, vb.y), pack2(vb.z, vb.w));
  } else if (u < 139264) {     // W1 frags: 16hc x 8c x 64l
    const int u2 = u - 131072;
    const int l = u2 & 63, c = (u2 >> 6) & 7, hc = u2 >> 9;
    const int fr = l & 15, fq = l >> 4;
    const float* p = W1 + (size_t)((fr >= 8) ? 256 : 0) * 128 +
                     (size_t)(c * 32 + fq * 8) * 128 + hc * 8 + (fr & 7);
    float v[8];
#pragma unroll
    for (int j = 0; j < 8; ++j) v[j] = p[(size_t)j * 128];
    w1f[u2] = make_uint4(pack2(v[0], v[1]), pack2(v[2], v[3]),
                         pack2(v[4], v[5]), pack2(v[6], v[7]));
  } else if (u < 143360) {     // W2 frags: 16dg x 4c x 64l
    const int u3 = u - 139264;
    const int l = u3 & 63, c = (u3 >> 6) & 3, dg = u3 >> 8;
    const int fr = l & 15, fq = l >> 4;
    const float* p = W2 + (size_t)(c * 32 + fq * 8) * 256 + dg * 16 + fr;
    float v[8];
#pragma unroll
    for (int j = 0; j < 8; ++j) v[j] = p[(size_t)j * 256];
    w2f[u3] = make_uint4(pack2(v[0], v[1]), pack2(v[2], v[3]),
                         pack2(v[4], v[5]), pack2(v[6], v[7]));
  }
}

// ---------------------------------------------------------------------------
// kA (r15-verbatim body, DIAGNOSTIC rep=6 loop; idempotent — each rep fully
// recomputes As/Cs from global before reuse; trailing barrier protects the
// As mh-overwrite across reps).  Block (b, hc), 1024 thr = 16 waves.
// ---------------------------------------------------------------------------
__global__ __launch_bounds__(1024) void kA(
    const uint4* __restrict__ xbf, const uint4* __restrict__ w1f,
    const float* __restrict__ b1, uint4* __restrict__ mf)
{
  __shared__ float Cs[8][260];
  __shared__ float As[8][260];      // a-values; overwritten in-place by mh
  __shared__ float sortedC[8][256];
  __shared__ float sufS[8][260];    // suffix sums; sufS[hp][256] = 0

  const int tid = threadIdx.x, lane = tid & 63, wv = tid >> 6;  // wv 0..15
  const int b = blockIdx.x, hc = blockIdx.y;
  const int fr = lane & 15, fq = lane >> 4;

  for (int rep = 0; rep < 6; ++rep) {
    asm volatile("" ::: "memory");   // force per-rep reloads (r10 pattern)

    FragU afr[8];
#pragma unroll
    for (int c = 0; c < 8; ++c) afr[c].q = w1f[(hc * 8 + c) * 64 + lane];

    float b1v[4];
#pragma unroll
    for (int g = 0; g < 4; ++g)
      b1v[g] = (fq >= 2) ? b1[hc * 8 + (fq - 2) * 4 + g] : 0.f;

    {  // ---- phase 1: MFMA, wave = m-tile ----
      const int t = wv;
      f32x4 acc = {0.f, 0.f, 0.f, 0.f};
#pragma unroll
      for (int c = 0; c < 8; ++c) {
        FragU bfr;
        bfr.q = xbf[((size_t)(b * 16 + t) * 8 + c) * 64 + lane];
        acc = __builtin_amdgcn_mfma_f32_16x16x32_bf16(afr[c].h, bfr.h, acc, 0, 0, 0);
      }
      const int m = t * 16 + fr;
      if (fq < 2) {
#pragma unroll
        for (int g = 0; g < 4; ++g) As[fq * 4 + g][m] = acc[g];
      } else {
#pragma unroll
        for (int g = 0; g < 4; ++g) Cs[(fq - 2) * 4 + g][m] = acc[g] + b1v[g];
      }
    }
    __syncthreads();

    // ---- phase 1.5: waves 0..7 sort Cs[wv] (bitonic, 4 regs/lane) ----
    if (wv < 8) {
      const int hp = wv;
      float v0 = Cs[hp][lane * 4 + 0], v1 = Cs[hp][lane * 4 + 1];
      float v2 = Cs[hp][lane * 4 + 2], v3 = Cs[hp][lane * 4 + 3];

#define CE2(X, Y, UP)                                     \
      {                                                   \
        float mn = fminf(X, Y), mx = fmaxf(X, Y);         \
        X = (UP) ? mn : mx;  Y = (UP) ? mx : mn;          \
      }
      CE2(v0, v1, true) CE2(v2, v3, false)
      {
        const bool up4 = (lane & 1) == 0;
        CE2(v0, v2, up4) CE2(v1, v3, up4)
        CE2(v0, v1, up4) CE2(v2, v3, up4)
      }
#pragma unroll
      for (int k4 = 2; k4 <= 64; k4 <<= 1) {
        const bool up = (lane & k4) == 0;
#pragma unroll
        for (int j4 = k4 >> 1; j4 >= 1; j4 >>= 1) {
          const bool keepMin = (((lane & j4) == 0) == up);
#define CEX(V)                                            \
          {                                               \
            float o = __shfl_xor(V, j4, 64);              \
            V = keepMin ? fminf(V, o) : fmaxf(V, o);      \
          }
          CEX(v0) CEX(v1) CEX(v2) CEX(v3)
#undef CEX
        }
        CE2(v0, v2, up) CE2(v1, v3, up)
        CE2(v0, v1, up) CE2(v2, v3, up)
      }
#undef CE2

      const float sl = (v0 + v1) + (v2 + v3);
      float inc = sl;
#pragma unroll
      for (int off = 1; off < 64; off <<= 1) {
        float t = __shfl_down(inc, off, 64);
        inc += (lane + off < 64) ? t : 0.f;
      }
      const float T = inc - sl;
      const float su3 = T + v3;
      const float su2 = su3 + v2;
      const float su1 = su2 + v1;
      const float su0 = su1 + v0;
      sortedC[hp][lane * 4 + 0] = v0;
      sortedC[hp][lane * 4 + 1] = v1;
      sortedC[hp][lane * 4 + 2] = v2;
      sortedC[hp][lane * 4 + 3] = v3;
      sufS[hp][lane * 4 + 0] = su0;
      sufS[hp][lane * 4 + 1] = su1;
      sufS[hp][lane * 4 + 2] = su2;
      sufS[hp][lane * 4 + 3] = su3;
      if (lane == 0) sufS[hp][256] = 0.f;
    }
    __syncthreads();

    // ---- phase 2: binary search; wave (hp, half), 2 m each ----
    {
      const int hp = wv & 7, half = wv >> 3;
#pragma unroll
      for (int q = 0; q < 2; ++q) {
        const int m = half * 128 + q * 64 + lane;
        const float a = As[hp][m];
        const float t = -a;
        int idx = 0;
#pragma unroll
        for (int st = 128; st >= 1; st >>= 1)
          idx += (sortedC[hp][idx + st - 1] <= t) ? st : 0;
        const float cnt = (float)(256 - idx);
        const float S = sufS[hp][idx];
        As[hp][m] = (cnt * a + S) * (1.f / 256.f);
      }
    }
    __syncthreads();

    // ---- phase 3: pack row m=tid into kB fragment layout ----
    if (tid < 256) {
      const int fr2 = tid & 15, T2 = tid >> 4;
      uint4 o = make_uint4(pack2(As[0][tid], As[1][tid]), pack2(As[2][tid], As[3][tid]),
                           pack2(As[4][tid], As[5][tid]), pack2(As[6][tid], As[7][tid]));
      mf[((size_t)(b * 16 + T2) * 4 + (hc >> 2)) * 64 + (hc & 3) * 16 + fr2] = o;
    }
    __syncthreads();   // As overwritten next rep — protect readers
  }
}

// ---------------------------------------------------------------------------
// kB (r8-verbatim): out[m][d] = mh@W2 + b2 + x. Grid (256,4) x 256 thr.
// ---------------------------------------------------------------------------
__global__ __launch_bounds__(256) void kB(
    const uint4* __restrict__ mf, const uint4* __restrict__ w2f,
    const float* __restrict__ b2, const float* __restrict__ x,
    float* __restrict__ out)
{
  const int tid = threadIdx.x, lane = tid & 63, wu = tid >> 6;
  const int mt = blockIdx.x;
  const int dg = blockIdx.y * 4 + wu;
  const int fr = lane & 15, fq = lane >> 4;

  f32x4 acc = {0.f, 0.f, 0.f, 0.f};
#pragma unroll
  for (int c = 0; c < 4; ++c) {
    FragU a, bb;
    a.q  = mf[((size_t)mt * 4 + c) * 64 + lane];
    bb.q = w2f[((size_t)dg * 4 + c) * 64 + lane];
    acc = __builtin_amdgcn_mfma_f32_16x16x32_bf16(a.h, bb.h, acc, 0, 0, 0);
  }

  const int d = dg * 16 + fr;
  const float bv = b2[d];
#pragma unroll
  for (int g = 0; g < 4; ++g) {
    const int m = mt * 16 + fq * 4 + g;
    const size_t o = (size_t)m * 256 + d;
    out[o] = acc[g] + bv + x[o];
  }
}

extern "C" void kernel_launch(void* const* d_in, const int* in_sizes, int n_in,
                              void* d_out, int out_size, void* d_ws, size_t ws_size,
                              hipStream_t stream) {
  const float* x  = (const float*)d_in[0];
  const float* W1 = (const float*)d_in[1];
  const float* b1 = (const float*)d_in[2];
  const float* W2 = (const float*)d_in[3];
  const float* b2 = (const float*)d_in[4];
  float* out = (float*)d_out;

  char* ws = (char*)d_ws;
  uint4* xbf = (uint4*)ws;                               // 131072 u = 2 MB
  uint4* w1f = (uint4*)(ws + (2u << 20));                // 8192 u = 128 KB
  uint4* w2f = (uint4*)(ws + (2u << 20) + (128u << 10)); // 4096 u = 64 KB
  uint4* mf  = (uint4*)(ws + (2u << 20) + (192u << 10)); // 65536 u = 1 MB

  kX<<<560, 256, 0, stream>>>(x, W1, W2, xbf, w1f, w2f);
  kA<<<dim3(16, 16), 1024, 0, stream>>>(xbf, w1f, b1, mf);
  kB<<<dim3(256, 4), 256, 0, stream>>>(mf, w2f, b2, x, out);
}

// Round 17
// 21.851 us; speedup vs baseline: 2.4640x; 2.4640x over previous
//
#include <hip/hip_runtime.h>

typedef __attribute__((ext_vector_type(8))) short bf16x8;
typedef __attribute__((ext_vector_type(4))) float f32x4;

union FragU { uint4 q; bf16x8 h; };

__device__ __forceinline__ unsigned short f2bf(float f) {
  unsigned u = __float_as_uint(f);
  u += 0x7FFFu + ((u >> 16) & 1u);   // RNE
  return (unsigned short)(u >> 16);
}
__device__ __forceinline__ unsigned pack2(float lo, float hi) {
  return (unsigned)f2bf(lo) | ((unsigned)f2bf(hi) << 16);
}

// ---------------------------------------------------------------------------
// kX (r8 logic, 140 blocks x 1024 thr): cast into MFMA-fragment layouts.
// Region boundaries are block-aligned (128 / 136 / 140).
// ---------------------------------------------------------------------------
__global__ __launch_bounds__(1024) void kX(
    const float* __restrict__ x, const float* __restrict__ W1,
    const float* __restrict__ W2, uint4* __restrict__ xbf,
    uint4* __restrict__ w1f, uint4* __restrict__ w2f)
{
  const int u = blockIdx.x * 1024 + threadIdx.x;
  if (u < 131072) {            // x frags: 16b x 16t x 8c x 64l
    const int l = u & 63, c = (u >> 6) & 7, t = (u >> 9) & 15, b = u >> 13;
    const int fr = l & 15, fq = l >> 4;
    const float* p = x + (size_t)((b * 16 + t) * 16 + fr) * 256 + c * 32 + fq * 8;
    float4 va = *(const float4*)p;
    float4 vb = *(const float4*)(p + 4);
    xbf[u] = make_uint4(pack2(va.x, va.y), pack2(va.z, va.w),
                        pack2(vb.x, vb.y), pack2(vb.z, vb.w));
  } else if (u < 139264) {     // W1 frags: 16hc x 8c x 64l
    const int u2 = u - 131072;
    const int l = u2 & 63, c = (u2 >> 6) & 7, hc = u2 >> 9;
    const int fr = l & 15, fq = l >> 4;
    const float* p = W1 + (size_t)((fr >= 8) ? 256 : 0) * 128 +
                     (size_t)(c * 32 + fq * 8) * 128 + hc * 8 + (fr & 7);
    float v[8];
#pragma unroll
    for (int j = 0; j < 8; ++j) v[j] = p[(size_t)j * 128];
    w1f[u2] = make_uint4(pack2(v[0], v[1]), pack2(v[2], v[3]),
                         pack2(v[4], v[5]), pack2(v[6], v[7]));
  } else if (u < 143360) {     // W2 frags: 16dg x 4c x 64l
    const int u3 = u - 139264;
    const int l = u3 & 63, c = (u3 >> 6) & 3, dg = u3 >> 8;
    const int fr = l & 15, fq = l >> 4;
    const float* p = W2 + (size_t)(c * 32 + fq * 8) * 256 + dg * 16 + fr;
    float v[8];
#pragma unroll
    for (int j = 0; j < 8; ++j) v[j] = p[(size_t)j * 256];
    w2f[u3] = make_uint4(pack2(v[0], v[1]), pack2(v[2], v[3]),
                         pack2(v[4], v[5]), pack2(v[6], v[7]));
  }
}

// ---------------------------------------------------------------------------
// kA: 512 thr = 8 waves (all waves active in every phase).
//  p1 : wave wv does m-tiles {wv, wv+8} (afr reused) -> As (a), Cs (c+b1).
//  p1.5: wave wv bitonic-sorts Cs[wv] (4 regs/lane) + suffix scan; exports
//        sortedC, 16 pivots Piv[j]=sortedC[16j+15], sufBlk[j]=sufS[16(j+1)].
//  p2 : wave wv -> hp=wv, 4 m/lane. p = #(Piv<=t) via 16 broadcast-read
//       compares; leaf = 4 indep b128 + sufBlk[p] (parallel); exact
//       Σrelu = cnt·a + S.  Serial LDS depth 1 (was 8).
//  p3 : 512 thr pack mh into kB fragment layout (uint2 halves).
// Grid (16,16) = 256 blocks, ~26 KB LDS.
// ---------------------------------------------------------------------------
__global__ __launch_bounds__(512) void kA(
    const uint4* __restrict__ xbf, const uint4* __restrict__ w1f,
    const float* __restrict__ b1, uint4* __restrict__ mf)
{
  __shared__ float Cs[8][260];
  __shared__ float As[8][260];      // a-values; overwritten in-place by mh
  __shared__ float sortedC[8][256];
  __shared__ float Piv[8][16];
  __shared__ float sufBlk[8][16];

  const int tid = threadIdx.x, lane = tid & 63, wv = tid >> 6;  // wv 0..7
  const int b = blockIdx.x, hc = blockIdx.y;
  const int fr = lane & 15, fq = lane >> 4;

  FragU afr[8];
#pragma unroll
  for (int c = 0; c < 8; ++c) afr[c].q = w1f[(hc * 8 + c) * 64 + lane];

  float b1v[4];
#pragma unroll
  for (int g = 0; g < 4; ++g)
    b1v[g] = (fq >= 2) ? b1[hc * 8 + (fq - 2) * 4 + g] : 0.f;

  // ---- phase 1: MFMA; wave wv does m-tiles wv and wv+8 ----
#pragma unroll
  for (int s = 0; s < 2; ++s) {
    const int t = wv + s * 8;
    f32x4 acc = {0.f, 0.f, 0.f, 0.f};
#pragma unroll
    for (int c = 0; c < 8; ++c) {
      FragU bfr;
      bfr.q = xbf[((size_t)(b * 16 + t) * 8 + c) * 64 + lane];
      acc = __builtin_amdgcn_mfma_f32_16x16x32_bf16(afr[c].h, bfr.h, acc, 0, 0, 0);
    }
    const int m = t * 16 + fr;
    if (fq < 2) {
#pragma unroll
      for (int g = 0; g < 4; ++g) As[fq * 4 + g][m] = acc[g];
    } else {
#pragma unroll
      for (int g = 0; g < 4; ++g) Cs[(fq - 2) * 4 + g][m] = acc[g] + b1v[g];
    }
  }
  __syncthreads();

  // ---- phase 1.5: wave wv sorts Cs[wv] (bitonic, 4 regs/lane) ----
  {
    const int hp = wv;
    float v0 = Cs[hp][lane * 4 + 0], v1 = Cs[hp][lane * 4 + 1];
    float v2 = Cs[hp][lane * 4 + 2], v3 = Cs[hp][lane * 4 + 3];

#define CE2(X, Y, UP)                                     \
    {                                                     \
      float mn = fminf(X, Y), mx = fmaxf(X, Y);           \
      X = (UP) ? mn : mx;  Y = (UP) ? mx : mn;            \
    }
    CE2(v0, v1, true) CE2(v2, v3, false)
    {
      const bool up4 = (lane & 1) == 0;
      CE2(v0, v2, up4) CE2(v1, v3, up4)
      CE2(v0, v1, up4) CE2(v2, v3, up4)
    }
#pragma unroll
    for (int k4 = 2; k4 <= 64; k4 <<= 1) {
      const bool up = (lane & k4) == 0;
#pragma unroll
      for (int j4 = k4 >> 1; j4 >= 1; j4 >>= 1) {
        const bool keepMin = (((lane & j4) == 0) == up);
#define CEX(V)                                            \
        {                                                 \
          float o = __shfl_xor(V, j4, 64);                \
          V = keepMin ? fminf(V, o) : fmaxf(V, o);        \
        }
        CEX(v0) CEX(v1) CEX(v2) CEX(v3)
#undef CEX
      }
      CE2(v0, v2, up) CE2(v1, v3, up)
      CE2(v0, v1, up) CE2(v2, v3, up)
    }
#undef CE2

    const float sl = (v0 + v1) + (v2 + v3);
    float inc = sl;
#pragma unroll
    for (int off = 1; off < 64; off <<= 1) {
      float t = __shfl_down(inc, off, 64);
      inc += (lane + off < 64) ? t : 0.f;
    }
    const float T = inc - sl;          // suffix strictly above this lane
    const float su3 = T + v3;
    const float su2 = su3 + v2;
    const float su1 = su2 + v1;
    const float su0 = su1 + v0;        // = sufS[lane*4]
    sortedC[hp][lane * 4 + 0] = v0;
    sortedC[hp][lane * 4 + 1] = v1;
    sortedC[hp][lane * 4 + 2] = v2;
    sortedC[hp][lane * 4 + 3] = v3;
    if ((lane & 3) == 3) Piv[hp][lane >> 2] = v3;          // sortedC[16j+15]
    if ((lane & 3) == 0 && lane) sufBlk[hp][(lane >> 2) - 1] = su0;  // sufS[16(j+1)]
    if (lane == 0) sufBlk[hp][15] = 0.f;                   // sufS[256]
  }
  __syncthreads();

  // ---- phase 2: exact relu-sum via 2-round search; wave wv -> hp=wv ----
  {
    const int hp = wv;
    float piv[16];
#pragma unroll
    for (int j = 0; j < 16; j += 4) {   // broadcast reads (uniform addr)
      float4 pv = *(const float4*)&Piv[hp][j];
      piv[j] = pv.x; piv[j + 1] = pv.y; piv[j + 2] = pv.z; piv[j + 3] = pv.w;
    }
#pragma unroll
    for (int q = 0; q < 4; ++q) {
      const int m = q * 64 + lane;
      const float a = As[hp][m];
      const float t = -a;
      int p = 0;
#pragma unroll
      for (int j = 0; j < 16; ++j) p += (piv[j] <= t) ? 1 : 0;
      p = (p > 15) ? 15 : p;
      const float Sb = sufBlk[hp][p];            // 1 dependent b32
      const float* leafp = &sortedC[hp][p * 16]; // 4 indep b128
      float sumL = 0.f; int cntL = 0;
#pragma unroll
      for (int j = 0; j < 16; j += 4) {
        float4 lv = *(const float4*)&leafp[j];
        if (lv.x > t) { sumL += lv.x; ++cntL; }
        if (lv.y > t) { sumL += lv.y; ++cntL; }
        if (lv.z > t) { sumL += lv.z; ++cntL; }
        if (lv.w > t) { sumL += lv.w; ++cntL; }
      }
      const float cnt = (float)(240 - 16 * p + cntL);
      As[hp][m] = (cnt * a + (Sb + sumL)) * (1.f / 256.f);
    }
  }
  __syncthreads();

  // ---- phase 3: 512 thr pack rows; thread = (m = tid>>1, half = tid&1) ----
  {
    const int m = tid >> 1, half = tid & 1, j0 = half * 4;
    const int fr2 = m & 15, T2 = m >> 4;
    uint2 o = make_uint2(pack2(As[j0][m], As[j0 + 1][m]),
                         pack2(As[j0 + 2][m], As[j0 + 3][m]));
    const size_t unit = ((size_t)(b * 16 + T2) * 4 + (hc >> 2)) * 64 + (hc & 3) * 16 + fr2;
    *(uint2*)((unsigned*)mf + unit * 4 + half * 2) = o;
  }
}

// ---------------------------------------------------------------------------
// kB (r8 logic, 256 blocks x 1024 thr): wave wu = d-group dg.
// ---------------------------------------------------------------------------
__global__ __launch_bounds__(1024) void kB(
    const uint4* __restrict__ mf, const uint4* __restrict__ w2f,
    const float* __restrict__ b2, const float* __restrict__ x,
    float* __restrict__ out)
{
  const int tid = threadIdx.x, lane = tid & 63, wu = tid >> 6;
  const int mt = blockIdx.x;     // 0..255
  const int dg = wu;             // 0..15
  const int fr = lane & 15, fq = lane >> 4;

  f32x4 acc = {0.f, 0.f, 0.f, 0.f};
#pragma unroll
  for (int c = 0; c < 4; ++c) {
    FragU a, bb;
    a.q  = mf[((size_t)mt * 4 + c) * 64 + lane];
    bb.q = w2f[((size_t)dg * 4 + c) * 64 + lane];
    acc = __builtin_amdgcn_mfma_f32_16x16x32_bf16(a.h, bb.h, acc, 0, 0, 0);
  }

  const int d = dg * 16 + fr;
  const float bv = b2[d];
#pragma unroll
  for (int g = 0; g < 4; ++g) {
    const int m = mt * 16 + fq * 4 + g;
    const size_t o = (size_t)m * 256 + d;
    out[o] = acc[g] + bv + x[o];
  }
}

extern "C" void kernel_launch(void* const* d_in, const int* in_sizes, int n_in,
                              void* d_out, int out_size, void* d_ws, size_t ws_size,
                              hipStream_t stream) {
  const float* x  = (const float*)d_in[0];
  const float* W1 = (const float*)d_in[1];
  const float* b1 = (const float*)d_in[2];
  const float* W2 = (const float*)d_in[3];
  const float* b2 = (const float*)d_in[4];
  float* out = (float*)d_out;

  char* ws = (char*)d_ws;
  uint4* xbf = (uint4*)ws;                               // 131072 u = 2 MB
  uint4* w1f = (uint4*)(ws + (2u << 20));                // 8192 u = 128 KB
  uint4* w2f = (uint4*)(ws + (2u << 20) + (128u << 10)); // 4096 u = 64 KB
  uint4* mf  = (uint4*)(ws + (2u << 20) + (192u << 10)); // 65536 u = 1 MB

  kX<<<140, 1024, 0, stream>>>(x, W1, W2, xbf, w1f, w2f);
  kA<<<dim3(16, 16), 512, 0, stream>>>(xbf, w1f, b1, mf);
  kB<<<256, 1024, 0, stream>>>(mf, w2f, b2, x, out);
}